// Round 9
// baseline (377.272 us; speedup 1.0000x reference)
//
#include <hip/hip_runtime.h>
#include <stdint.h>

#define L_SEQ 2048
#define S_SEQ 2048
#define NB 2
#define EMB 1024
#define NH 16
#define DH 64
#define NC 32
#define MROWS 4096  // L*N

typedef __bf16 bf16x8 __attribute__((ext_vector_type(8)));
typedef float f32x4 __attribute__((ext_vector_type(4)));

__device__ __forceinline__ float bf2f(unsigned short u) {
  return __builtin_bit_cast(float, (uint32_t)u << 16);
}
__device__ __forceinline__ unsigned short f2bf(float f) {
  uint32_t u = __builtin_bit_cast(uint32_t, f);
  return (unsigned short)((u + 0x7FFFu + ((u >> 16) & 1u)) >> 16);
}

// Async global->LDS staging (m97 lever). LDS dest is wave-uniform base + lane*16 in our
// staging pattern (consecutive tid -> consecutive 16B LDS chunks), which is the documented
// contract. Fallback: plain vector copy (same data, VGPR round-trip).
#if defined(__has_builtin) && __has_builtin(__builtin_amdgcn_global_load_lds)
#define GLOAD_LDS(gp, lp)                                            \
  __builtin_amdgcn_global_load_lds(                                  \
      (const __attribute__((address_space(1))) void*)(gp),           \
      (__attribute__((address_space(3))) void*)(lp), 16, 0, 0)
#else
#define GLOAD_LDS(gp, lp) do { *(uint4*)(lp) = *(const uint4*)(gp); } while (0)
#endif

// f32 -> bf16 RNE convert for W (region 1) + X (region 2) in ONE launch (launch-count diet).
// Same f2bf as validated inline path -> bit-identical GEMM inputs. srcX may be null.
__global__ void __launch_bounds__(256) conv_f2bf_kernel(
    const float* __restrict__ srcW, unsigned short* __restrict__ dstW, int nW8,
    const float* __restrict__ srcX, unsigned short* __restrict__ dstX, int nX8)
{
  int id = blockIdx.x * 256 + threadIdx.x;
  const float* src; unsigned short* dst; int i;
  if (id < nW8) { src = srcW; dst = dstW; i = id; }
  else { i = id - nW8; if (i >= nX8) return; src = srcX; dst = dstX; }
  const float4* s = (const float4*)src + (size_t)i * 2;
  float4 a0 = s[0], a1 = s[1];
  uint4 u;
  u.x = (uint32_t)f2bf(a0.x) | ((uint32_t)f2bf(a0.y) << 16);
  u.y = (uint32_t)f2bf(a0.z) | ((uint32_t)f2bf(a0.w) << 16);
  u.z = (uint32_t)f2bf(a1.x) | ((uint32_t)f2bf(a1.y) << 16);
  u.w = (uint32_t)f2bf(a1.z) | ((uint32_t)f2bf(a1.w) << 16);
  ((uint4*)dst)[i] = u;
}

// C = A @ B^T + bias. MFMA bf16, 128x128 tile (m93/m97-validated frag/epilogue structure).
// Both operands bf16 (pre-converted) -> staging is pure global_load_lds width-16
// (4 calls/thread/K-step), no VALU conversion in the loop. Out: f32 if outF, else bf16.
__global__ void __launch_bounds__(256) gemm_bt_mfma(
    const unsigned short* __restrict__ A, const unsigned short* __restrict__ B,
    const float* __restrict__ bias,
    float* __restrict__ outF, unsigned short* __restrict__ outB)
{
  __shared__ __align__(16) unsigned short As[128][32];  // unpadded 64B rows (b128-aligned)
  __shared__ __align__(16) unsigned short Bs[128][32];
  const int K = EMB;
  int tid = threadIdx.x;
  int m0 = blockIdx.y * 128, n0 = blockIdx.x * 128;
  int wave = tid >> 6, lane = tid & 63;
  int wm = (wave >> 1) * 64, wn = (wave & 1) * 64;

  f32x4 zero = {0.f, 0.f, 0.f, 0.f};
  f32x4 acc[4][4];
#pragma unroll
  for (int mi = 0; mi < 4; mi++)
#pragma unroll
    for (int ni = 0; ni < 4; ni++) acc[mi][ni] = zero;

  int fr = lane & 15, fk = (lane >> 4) * 8;

  for (int k0 = 0; k0 < K; k0 += 32) {
    __syncthreads();
#pragma unroll
    for (int it = 0; it < 2; it++) {
      int ch = tid + it * 256;          // 512 chunks of 8 bf16 per tile
      int row = ch >> 2, kk = (ch & 3) * 8;
      GLOAD_LDS(A + (size_t)(m0 + row) * K + k0 + kk, &As[row][kk]);
      GLOAD_LDS(B + (size_t)(n0 + row) * K + k0 + kk, &Bs[row][kk]);
    }
    __syncthreads();
    bf16x8 af[4], bfr[4];
#pragma unroll
    for (int i = 0; i < 4; i++) af[i] = *(const bf16x8*)(&As[wm + i * 16 + fr][fk]);
#pragma unroll
    for (int i = 0; i < 4; i++) bfr[i] = *(const bf16x8*)(&Bs[wn + i * 16 + fr][fk]);
#pragma unroll
    for (int mi = 0; mi < 4; mi++)
#pragma unroll
      for (int ni = 0; ni < 4; ni++)
        acc[mi][ni] = __builtin_amdgcn_mfma_f32_16x16x32_bf16(af[mi], bfr[ni], acc[mi][ni], 0, 0, 0);
  }

#pragma unroll
  for (int ni = 0; ni < 4; ni++) {
    int col = n0 + wn + ni * 16 + (lane & 15);
    float bv = bias[col];
#pragma unroll
    for (int mi = 0; mi < 4; mi++) {
#pragma unroll
      for (int r = 0; r < 4; r++) {
        int row = m0 + wm + mi * 16 + (lane >> 4) * 4 + r;
        float v = acc[mi][ni][r] + bv;
        if (outF) outF[(size_t)row * EMB + col] = v;
        else outB[(size_t)row * EMB + col] = f2bf(v);
      }
    }
  }
}

// prep stage 1: partial[es][c][k] = sum_{e in es-chunk, ascending} W[e][k]*cent[c][e], f64.
// (R7-validated: prep family now ~7us.) W reads coalesced 256B row-runs; cent rows
// wave-uniform (readfirstlane -> s_load); 8 independent f64 FMA chains.
__global__ void __launch_bounds__(256) prep_partial_kernel(
    const float* __restrict__ Wq_, const float* __restrict__ cq_,
    const float* __restrict__ Wk_, const float* __restrict__ ck_,
    double* __restrict__ partQ, double* __restrict__ partK)
{
  const float* W; const float* cent; double* part;
  if (blockIdx.z == 0) { W = Wq_; cent = cq_; part = partQ; }
  else                 { W = Wk_; cent = ck_; part = partK; }
  int tid = threadIdx.x;
  int k = (blockIdx.y << 6) | (tid & 63);
  int cbase = __builtin_amdgcn_readfirstlane(tid >> 6) * 8;   // wave-uniform -> s_load path
  int e0 = blockIdx.x << 6;

  double acc[8];
#pragma unroll
  for (int j = 0; j < 8; j++) acc[j] = 0.0;

#pragma unroll 2
  for (int e = 0; e < 64; e++) {
    double w = (double)W[(size_t)(e0 + e) * EMB + k];
#pragma unroll
    for (int j = 0; j < 8; j++)
      acc[j] += w * (double)cent[(size_t)(cbase + j) * EMB + e0 + e];
  }
#pragma unroll
  for (int j = 0; j < 8; j++)
    part[((size_t)blockIdx.x * NC + cbase + j) * EMB + k] = acc[j];
}

// prep stage 2: WcT[k][c] = sum_{es ascending} partial[es][c][k]  (globally e-ascending
// f64 order, deterministic).
__global__ void __launch_bounds__(256) prep_reduce_kernel(
    const double* __restrict__ partQ, const double* __restrict__ partK,
    double* __restrict__ WcTq, double* __restrict__ WcTk)
{
  int id = blockIdx.x * 256 + threadIdx.x;        // 0 .. 2*NC*EMB-1
  const double* part; double* WcT; int local;
  if (id < NC * EMB) { part = partQ; WcT = WcTq; local = id; }
  else               { part = partK; WcT = WcTk; local = id - NC * EMB; }
  int c = local >> 10, k = local & 1023;
  double s = 0.0;
  for (int es = 0; es < 16; es++)
    s += part[((size_t)es * NC + c) * EMB + k];
  WcT[(size_t)k * NC + c] = s;
}

// bd[c] = sum_e bias[e]*cent[c][e] — bit-identical replica of the original bd path
// (8 g-groups of 128 consecutive e, then g-ordered sum). blockIdx.x: 0=q, 1=k.
__global__ void __launch_bounds__(256) prep_bd_kernel(
    const float* __restrict__ bq_, const float* __restrict__ cq_,
    const float* __restrict__ bk_, const float* __restrict__ ck_,
    double* __restrict__ bdq, double* __restrict__ bdk)
{
  const float* bias; const float* cent; double* bd;
  if (blockIdx.x == 0) { bias = bq_; cent = cq_; bd = bdq; }
  else                 { bias = bk_; cent = ck_; bd = bdk; }
  int tid = threadIdx.x;
  int c = tid & 31, g = tid >> 5;
  __shared__ double red[8][32];
  double s2 = 0.0;
  for (int e = g * 128; e < (g + 1) * 128; e++)
    s2 += (double)bias[e] * (double)cent[(size_t)c * EMB + e];
  red[g][c] = s2;
  __syncthreads();
  if (tid < 32) {
    double t = 0.0;
#pragma unroll
    for (int gg = 0; gg < 8; gg++) t += red[gg][tid];
    bd[tid] = t;
  }
}

// Assignment from RAW f32 input rows via WcT: f64 dots, first-max argmax.
// R8 post-mortem: X LDS broadcasts were 96 of ~152 LDS cyc/step AND occupancy fell to
// 1 wave/SIMD (grid 256) exposing latency. X has zero intra-thread reuse — broadcast is
// what VMEM does natively (32-lane same-addr load = 1 L1 transaction, separate pipe).
// This version reads X straight from global (float4, L1-streamed, 128 KB/block once) and
// keeps only W in LDS ([kk][c] f64, b64 2-way-free reads). FMA chain assignment and
// summation order BIT-IDENTICAL to R8 (same f32->f64 cvt at use) -> identical dots.
// Argmax/tie semantics identical. blockIdx.y: 0=query, 1=key.
__global__ void __launch_bounds__(256) assign2_kernel(
    const float* __restrict__ Xq, const double* __restrict__ WcTq, const double* __restrict__ bdq,
    int* __restrict__ qcl, int* __restrict__ qcnt,
    const float* __restrict__ Xk, const double* __restrict__ WcTk, const double* __restrict__ bdk,
    int* __restrict__ kcl, int* __restrict__ kcnt)
{
  const float* X; const double* WcT; const double* bd; int* cluster; int* count;
  if (blockIdx.y == 0) { X = Xq; WcT = WcTq; bd = bdq; cluster = qcl; count = qcnt; }
  else                 { X = Xk; WcT = WcTk; bd = bdk; cluster = kcl; count = kcnt; }

  int r0 = blockIdx.x * 32;                       // 32 rows/block
  int tid = threadIdx.x;
  int c = tid & 31, g = tid >> 5;                 // 8 groups x 4 rows
  int g4 = g * 4;

  __shared__ __align__(16) double Ws[64][32];     // [kk][c] f64, 16 KB (2-way reads = free)

  const float* xr0 = X + (size_t)(r0 + g4 + 0) * EMB;
  const float* xr1 = X + (size_t)(r0 + g4 + 1) * EMB;
  const float* xr2 = X + (size_t)(r0 + g4 + 2) * EMB;
  const float* xr3 = X + (size_t)(r0 + g4 + 3) * EMB;

  double a[4][4];                                 // 4 rows x 4 k-phase chains
#pragma unroll
  for (int rr = 0; rr < 4; rr++)
#pragma unroll
    for (int j = 0; j < 4; j++) a[rr][j] = 0.0;

  for (int k0 = 0; k0 < EMB; k0 += 64) {
    __syncthreads();                              // prev chunk compute done
    // stage WcT chunk: 2048 doubles, 8/thread, coalesced
#pragma unroll
    for (int it = 0; it < 8; it++) {
      int idx = it * 256 + tid;
      ((double*)Ws)[idx] = WcT[(size_t)k0 * NC + idx];
    }
    __syncthreads();                              // tile ready
#pragma unroll
    for (int ks = 0; ks < 64; ks += 8) {
      double w0 = Ws[ks + 0][c], w1 = Ws[ks + 1][c];
      double w2 = Ws[ks + 2][c], w3 = Ws[ks + 3][c];
      double w4 = Ws[ks + 4][c], w5 = Ws[ks + 5][c];
      double w6 = Ws[ks + 6][c], w7 = Ws[ks + 7][c];
      const float* xp[4] = { xr0, xr1, xr2, xr3 };
#pragma unroll
      for (int rr = 0; rr < 4; rr++) {
        float4 xa = *(const float4*)(xp[rr] + k0 + ks);      // VMEM broadcast (L1)
        float4 xb = *(const float4*)(xp[rr] + k0 + ks + 4);
        a[rr][0] += (double)xa.x * w0; a[rr][1] += (double)xa.y * w1;
        a[rr][2] += (double)xa.z * w2; a[rr][3] += (double)xa.w * w3;
        a[rr][0] += (double)xb.x * w4; a[rr][1] += (double)xb.y * w5;
        a[rr][2] += (double)xb.z * w6; a[rr][3] += (double)xb.w * w7;
      }
    }
  }

  double bdc = bd[c];
#pragma unroll
  for (int rr = 0; rr < 4; rr++) {
    double dot = ((a[rr][0] + a[rr][1]) + (a[rr][2] + a[rr][3])) + bdc;
    // argmax over c within each 32-lane half (first-max: lowest index wins ties)
    double bv = dot; int bi = c;
#pragma unroll
    for (int off = 1; off < 32; off <<= 1) {
      double ov = __shfl_xor(bv, off, 64);
      int oi = __shfl_xor(bi, off, 64);
      if (ov > bv || (ov == bv && oi < bi)) { bv = ov; bi = oi; }
    }
    if (c == 0) {
      int row = r0 + g4 + rr;
      cluster[row] = bi;
      atomicAdd(&count[(row & 1) * NC + bi], 1);
    }
  }
}

__global__ void scan_kernel(const int* __restrict__ qcount, const int* __restrict__ kcount,
                            int* __restrict__ qoff, int* __restrict__ koff)
{
  int tid = threadIdx.x;
  if (tid < 2) {
    int run = 0;
    for (int c = 0; c < NC; c++) { qoff[tid * NC + c] = run; run += qcount[tid * NC + c]; }
  } else if (tid < 4) {
    int n = tid - 2, run = 0;
    for (int c = 0; c < NC; c++) { koff[n * NC + c] = run; run += kcount[n * NC + c]; }
  }
}

__global__ void __launch_bounds__(256) scatter_kernel(
    const int* __restrict__ q_cluster, const int* __restrict__ k_cluster,
    const int* __restrict__ qoff, const int* __restrict__ koff,
    int* __restrict__ qfill, int* __restrict__ kfill,
    int* __restrict__ qlist, int* __restrict__ klist)
{
  int id = blockIdx.x * 256 + threadIdx.x;
  if (id < MROWS) {
    int row = id, n = row & 1, l = row >> 1, c = q_cluster[row];
    int pos = atomicAdd(&qfill[n * NC + c], 1);
    qlist[n * L_SEQ + qoff[n * NC + c] + pos] = l;
  } else {
    int row = id - MROWS, n = row & 1, s = row >> 1, c = k_cluster[row];
    int pos = atomicAdd(&kfill[n * NC + c], 1);
    klist[n * S_SEQ + koff[n * NC + c] + pos] = s;
  }
}

// Bucketed attention, MFMA flash-style. Block=(cluster,head,batch), 4 waves, 16 queries/wave,
// 64-key chunks with online softmax. Swapped operands keep softmax per-lane-uniform:
//   S^T = mfma(A=K, B=Q)    -> D[row=key=4g+r][col=q=lane&15]
//   O^T = mfma(A=V^T, B=P^T)-> D[row=d  =4g+r][col=q=lane&15]
// so running max / lsum / rescale are one scalar per lane (reduce = shfl_xor 16,32).
// P^T relayout through wave-private LDS; all LDS tiles row-XOR-swizzled. (R1-validated.)
__global__ void __launch_bounds__(256) attn_bucket(
    const unsigned short* __restrict__ Qb, const unsigned short* __restrict__ Kb,
    const unsigned short* __restrict__ Vb,
    const int* __restrict__ qcount, const int* __restrict__ qoff, const int* __restrict__ qlist,
    const int* __restrict__ kcount, const int* __restrict__ koff, const int* __restrict__ klist,
    unsigned short* __restrict__ ctx)
{
  int c = blockIdx.x, h = blockIdx.y, n = blockIdx.z;
  int Sc = kcount[n * NC + c], k0base = koff[n * NC + c];
  int Lc = qcount[n * NC + c], q0 = qoff[n * NC + c];
  int tid = threadIdx.x, wave = tid >> 6, lane = tid & 63;
  int lg = lane >> 4, lq = lane & 15;

  __shared__ __align__(16) unsigned short Ks[64][64];    // [key][d], row-swizzled
  __shared__ __align__(16) unsigned short Vts[64][64];   // [d][key], row-swizzled
  __shared__ __align__(16) unsigned short Pts[4][16][64]; // per-wave [q][key], row-swizzled
  __shared__ int rb[64];                                  // gathered K/V row base offsets

  if (Sc == 0) {   // no keys: ref softmax would be NaN; R9 proved this never occurs. Write 0.
    for (int qi = wave; qi < Lc; qi += 4) {
      int l = qlist[n * L_SEQ + q0 + qi];
      ctx[((size_t)(n * L_SEQ + l)) * EMB + h * DH + lane] = 0;
    }
    return;
  }

  const int* kl = klist + n * S_SEQ + k0base;
  const int* ql = qlist + n * L_SEQ + q0;
  f32x4 zero = {0.f, 0.f, 0.f, 0.f};

  for (int qb = 0; qb < Lc; qb += 64) {           // uniform trip count across waves
    int qq = qb + wave * 16 + lq;
    int qqc = qq < Lc ? qq : Lc - 1;              // clamp: padded lanes duplicate last query
    int lrow = ql[qqc];
    const unsigned short* qp = Qb + ((size_t)(lrow * NB + n)) * EMB + h * DH;
    bf16x8 qf0 = *(const bf16x8*)(qp + lg * 8);          // B=Q frag: col=q, k=d 0..31
    bf16x8 qf1 = *(const bf16x8*)(qp + 32 + lg * 8);     //                  d 32..63

    f32x4 acc[4];                                  // O^T: 4 d-tiles, col=q per lane
#pragma unroll
    for (int di = 0; di < 4; di++) acc[di] = zero;
    float m = -3.0e38f, lsum = 0.f;

    for (int kc = 0; kc < Sc; kc += 64) {
      __syncthreads();                             // prev chunk compute done
      if (tid < 64) {
        int jj = kc + tid; if (jj >= Sc) jj = Sc - 1;   // clamp-pad: valid finite rows
        rb[tid] = (kl[jj] * NB + n) * EMB + h * DH;
      }
      __syncthreads();                             // rb ready
#pragma unroll
      for (int it = 0; it < 2; it++) {
        int p = it * 256 + tid;                    // 512 pieces
        {                                          // K: [key][d] 16B pieces
          int row = p >> 3, seg = p & 7;
          uint4 u = *(const uint4*)(Kb + rb[row] + seg * 8);
          *(uint4*)(&Ks[row][(seg * 8) ^ ((row & 7) << 3)]) = u;
        }
        {                                          // V^T: gather column d, 8 keys
          int d = p & 63, kg = p >> 6;
          unsigned short v0 = Vb[rb[kg * 8 + 0] + d], v1 = Vb[rb[kg * 8 + 1] + d];
          unsigned short v2 = Vb[rb[kg * 8 + 2] + d], v3 = Vb[rb[kg * 8 + 3] + d];
          unsigned short v4 = Vb[rb[kg * 8 + 4] + d], v5 = Vb[rb[kg * 8 + 5] + d];
          unsigned short v6 = Vb[rb[kg * 8 + 6] + d], v7 = Vb[rb[kg * 8 + 7] + d];
          uint4 u;
          u.x = (uint32_t)v0 | ((uint32_t)v1 << 16);
          u.y = (uint32_t)v2 | ((uint32_t)v3 << 16);
          u.z = (uint32_t)v4 | ((uint32_t)v5 << 16);
          u.w = (uint32_t)v6 | ((uint32_t)v7 << 16);
          *(uint4*)(&Vts[d][(kg * 8) ^ ((d & 7) << 3)]) = u;
        }
      }
      __syncthreads();                             // K/V^T staged

      // S^T = K @ Q^T : 4 key-tiles x 2 d-steps
      f32x4 st[4];
#pragma unroll
      for (int ni = 0; ni < 4; ni++) st[ni] = zero;
#pragma unroll
      for (int ni = 0; ni < 4; ni++) {
        int row = ni * 16 + lq;
        bf16x8 kf0 = *(const bf16x8*)(&Ks[row][(lg * 8) ^ ((row & 7) << 3)]);
        bf16x8 kf1 = *(const bf16x8*)(&Ks[row][(32 + lg * 8) ^ ((row & 7) << 3)]);
        st[ni] = __builtin_amdgcn_mfma_f32_16x16x32_bf16(kf0, qf0, st[ni], 0, 0, 0);
        st[ni] = __builtin_amdgcn_mfma_f32_16x16x32_bf16(kf1, qf1, st[ni], 0, 0, 0);
      }

      // online softmax (per-lane scalar state; clamp-padded keys duplicate valid
      // scores so they cannot change the max; they are zeroed in p below)
      int lim = Sc - kc;
      float cm = -3.0e38f;
#pragma unroll
      for (int ni = 0; ni < 4; ni++) {
        st[ni] = st[ni] * 0.125f;                  // 1/sqrt(64)
#pragma unroll
        for (int r = 0; r < 4; r++) cm = fmaxf(cm, st[ni][r]);
      }
      cm = fmaxf(cm, __shfl_xor(cm, 16, 64));
      cm = fmaxf(cm, __shfl_xor(cm, 32, 64));
      float mn = fmaxf(m, cm);
      float fac = __expf(m - mn);
      m = mn;
      lsum *= fac;
#pragma unroll
      for (int di = 0; di < 4; di++) acc[di] = acc[di] * fac;

      // P^T -> LDS (bf16); lsum over ROUNDED p so O stays a true weighted average
#pragma unroll
      for (int ni = 0; ni < 4; ni++) {
        int kloc = ni * 16 + lg * 4;
        float p0 = (kloc + 0 < lim) ? __expf(st[ni][0] - mn) : 0.f;
        float p1 = (kloc + 1 < lim) ? __expf(st[ni][1] - mn) : 0.f;
        float p2 = (kloc + 2 < lim) ? __expf(st[ni][2] - mn) : 0.f;
        float p3 = (kloc + 3 < lim) ? __expf(st[ni][3] - mn) : 0.f;
        unsigned short b0 = f2bf(p0), b1 = f2bf(p1), b2 = f2bf(p2), b3 = f2bf(p3);
        lsum += bf2f(b0) + bf2f(b1) + bf2f(b2) + bf2f(b3);
        ushort4 u4; u4.x = b0; u4.y = b1; u4.z = b2; u4.w = b3;
        *(ushort4*)(&Pts[wave][lq][kloc ^ ((lq & 7) << 3)]) = u4;
      }

      // O^T += V^T @ P^T : 4 d-tiles x 2 key-steps
#pragma unroll
      for (int ks = 0; ks < 2; ks++) {
        bf16x8 pf = *(const bf16x8*)(&Pts[wave][lq][(ks * 32 + lg * 8) ^ ((lq & 7) << 3)]);
#pragma unroll
        for (int di = 0; di < 4; di++) {
          int row = di * 16 + lq;
          bf16x8 vf = *(const bf16x8*)(&Vts[row][(ks * 32 + lg * 8) ^ ((row & 7) << 3)]);
          acc[di] = __builtin_amdgcn_mfma_f32_16x16x32_bf16(vf, pf, acc[di], 0, 0, 0);
        }
      }
    }

    lsum += __shfl_xor(lsum, 16, 64);
    lsum += __shfl_xor(lsum, 32, 64);
    float rinv = 1.f / lsum;
    if (qq < Lc) {                                 // padded duplicates skip the store
      unsigned short* op = ctx + ((size_t)(n * L_SEQ + lrow)) * EMB + h * DH;
#pragma unroll
      for (int di = 0; di < 4; di++) {
        ushort4 o;
        o.x = f2bf(acc[di][0] * rinv);
        o.y = f2bf(acc[di][1] * rinv);
        o.z = f2bf(acc[di][2] * rinv);
        o.w = f2bf(acc[di][3] * rinv);
        *(ushort4*)(op + di * 16 + lg * 4) = o;    // d = di*16 + 4g + r, contiguous r
      }
    }
  }
}

// Residual + LayerNorm, f32 output. out row r = l*NB+n; proj row = n*L+l. (R9-validated.)
__global__ void __launch_bounds__(256) ln_kernel(
    const float* __restrict__ proj, const float* __restrict__ query,
    const float* __restrict__ gamma, const float* __restrict__ beta,
    float* __restrict__ out)
{
  int r = blockIdx.x;
  int l = r >> 1, n = r & 1;
  int tid = threadIdx.x, wave = tid >> 6, lane = tid & 63;
  float4 p = *(const float4*)(proj + ((size_t)(n * L_SEQ + l)) * EMB + tid * 4);
  float4 qu = *(const float4*)(query + (size_t)r * EMB + tid * 4);
  float res[4] = { p.x + qu.x, p.y + qu.y, p.z + qu.z, p.w + qu.w };
  float s1 = res[0] + res[1] + res[2] + res[3];
  float s2 = res[0] * res[0] + res[1] * res[1] + res[2] * res[2] + res[3] * res[3];
#pragma unroll
  for (int off = 32; off; off >>= 1) {
    s1 += __shfl_xor(s1, off, 64);
    s2 += __shfl_xor(s2, off, 64);
  }
  __shared__ float a1[4], a2[4];
  if (lane == 0) { a1[wave] = s1; a2[wave] = s2; }
  __syncthreads();
  float t1 = a1[0] + a1[1] + a1[2] + a1[3];
  float t2 = a2[0] + a2[1] + a2[2] + a2[3];
  float mu = t1 * (1.f / EMB);
  float var = fmaxf(t2 * (1.f / EMB) - mu * mu, 0.f);
  float rstd = 1.f / sqrtf(var + 1e-5f);
  float4 gu = *(const float4*)(gamma + tid * 4);
  float4 bu = *(const float4*)(beta + tid * 4);
  float4 o;
  o.x = (res[0] - mu) * rstd * gu.x + bu.x;
  o.y = (res[1] - mu) * rstd * gu.y + bu.y;
  o.z = (res[2] - mu) * rstd * gu.z + bu.z;
  o.w = (res[3] - mu) * rstd * gu.w + bu.w;
  *(float4*)(out + (size_t)r * EMB + tid * 4) = o;
}

extern "C" void kernel_launch(void* const* d_in, const int* in_sizes, int n_in,
                              void* d_out, int out_size, void* d_ws, size_t ws_size,
                              hipStream_t stream) {
  const float* query = (const float*)d_in[0];
  const float* key   = (const float*)d_in[1];
  const float* value = (const float*)d_in[2];
  const float* Wq = (const float*)d_in[3];
  const float* bq = (const float*)d_in[4];
  const float* Wk = (const float*)d_in[5];
  const float* bk = (const float*)d_in[6];
  const float* Wv = (const float*)d_in[7];
  const float* bv = (const float*)d_in[8];
  const float* Wo = (const float*)d_in[9];
  const float* bo = (const float*)d_in[10];
  const float* cq = (const float*)d_in[11];
  const float* ck = (const float*)d_in[12];
  const float* gamma = (const float*)d_in[13];
  const float* beta  = (const float*)d_in[14];
  float* out = (float*)d_out;   // f32 output (reference dtype)

  const size_t MB_EL = (size_t)MROWS * EMB;   // 4M elements

  // workspace (~35 MB): control block first, then bf16 tensors; proj aliases Qb+Kb;
  // xbf (bf16 input scratch) aliases ctx (dead until attention); wbf appended (2 MB);
  // prep partials (8 MB) alias Qb (dead until first GEMM, which runs after prep_reduce).
  int* q_cluster = (int*)d_ws;               // 16 KB
  int* k_cluster = q_cluster + MROWS;        // 16 KB
  int* qcount = k_cluster + MROWS;           // 6 x 64 ints contiguous (one memset)
  int* kcount = qcount + 64;
  int* qoff   = kcount + 64;
  int* koff   = qoff + 64;
  int* qfill  = koff + 64;
  int* kfill  = qfill + 64;
  int* qlist  = kfill + 64;                  // [2][2048]
  int* klist  = qlist + MROWS;               // [2][2048]
  double* Wcq = (double*)(klist + MROWS);    // 256 KB (offset 67072, 16B-aligned) [k][c] layout
  double* Wck = Wcq + (size_t)NC * EMB;      // 256 KB [k][c] layout
  double* bdq = Wck + (size_t)NC * EMB;
  double* bdk = bdq + NC;
  unsigned short* Qb  = (unsigned short*)(bdk + NC);  // 8 MB bf16, row = seq*2+n
  unsigned short* Kb  = Qb + MB_EL;                   // 8 MB
  unsigned short* Vb  = Kb + MB_EL;                   // 8 MB
  unsigned short* ctx = Vb + MB_EL;                   // 8 MB, row = n*L+l
  unsigned short* wbf = ctx + MB_EL;                  // 2 MB bf16 weight scratch (reused 4x)
  unsigned short* xbf = ctx;   // bf16 input scratch overlays ctx (dead until attn writes it)
  float* proj = (float*)Qb;    // 16 MB f32 overlays Qb+Kb (dead after attention)
  double* partQ = (double*)Qb; // 4 MB prep partials overlay Qb (consumed before GEMM 1)
  double* partK = partQ + (size_t)16 * NC * EMB;      // 4 MB

  const int W8 = (EMB * EMB) / 8;     // 131072 chunks
  const int X8 = (int)(MB_EL / 8);    // 524288 chunks
  const int CVT_BLK = (W8 + X8 + 255) / 256;   // fused W+X convert grid

  hipMemsetAsync(qcount, 0, 6 * 64 * sizeof(int), stream);

  prep_partial_kernel<<<dim3(16, 16, 2), 256, 0, stream>>>(Wq, cq, Wk, ck, partQ, partK);
  prep_reduce_kernel<<<(2 * NC * EMB) / 256, 256, 0, stream>>>(partQ, partK, Wcq, Wck);
  prep_bd_kernel<<<2, 256, 0, stream>>>(bq, cq, bk, ck, bdq, bdk);

  dim3 gg(EMB / 128, MROWS / 128);
  conv_f2bf_kernel<<<CVT_BLK, 256, 0, stream>>>(Wq, wbf, W8, query, xbf, X8);
  gemm_bt_mfma<<<gg, 256, 0, stream>>>(xbf, wbf, bq, nullptr, Qb);

  conv_f2bf_kernel<<<CVT_BLK, 256, 0, stream>>>(Wk, wbf, W8, key, xbf, X8);
  gemm_bt_mfma<<<gg, 256, 0, stream>>>(xbf, wbf, bk, nullptr, Kb);

  conv_f2bf_kernel<<<CVT_BLK, 256, 0, stream>>>(Wv, wbf, W8, value, xbf, X8);
  gemm_bt_mfma<<<gg, 256, 0, stream>>>(xbf, wbf, bv, nullptr, Vb);

  assign2_kernel<<<dim3(MROWS / 32, 2), 256, 0, stream>>>(
      query, Wcq, bdq, q_cluster, qcount,
      key,   Wck, bdk, k_cluster, kcount);

  scan_kernel<<<1, 64, 0, stream>>>(qcount, kcount, qoff, koff);
  scatter_kernel<<<(2 * MROWS) / 256, 256, 0, stream>>>(q_cluster, k_cluster, qoff, koff,
                                                        qfill, kfill, qlist, klist);
  attn_bucket<<<dim3(NC, NH, NB), 256, 0, stream>>>(Qb, Kb, Vb, qcount, qoff, qlist,
                                                    kcount, koff, klist, ctx);

  conv_f2bf_kernel<<<(W8 + 255) / 256, 256, 0, stream>>>(Wo, wbf, W8, nullptr, nullptr, 0);
  gemm_bt_mfma<<<gg, 256, 0, stream>>>(ctx, wbf, bo, proj, nullptr);
  ln_kernel<<<MROWS, 256, 0, stream>>>(proj, query, gamma, beta, out);
}

// Round 10
// 331.784 us; speedup vs baseline: 1.1371x; 1.1371x over previous
//
#include <hip/hip_runtime.h>
#include <stdint.h>

#define L_SEQ 2048
#define S_SEQ 2048
#define NB 2
#define EMB 1024
#define NH 16
#define DH 64
#define NC 32
#define MROWS 4096  // L*N

typedef __bf16 bf16x8 __attribute__((ext_vector_type(8)));
typedef float f32x4 __attribute__((ext_vector_type(4)));

__device__ __forceinline__ float bf2f(unsigned short u) {
  return __builtin_bit_cast(float, (uint32_t)u << 16);
}
__device__ __forceinline__ unsigned short f2bf(float f) {
  uint32_t u = __builtin_bit_cast(uint32_t, f);
  return (unsigned short)((u + 0x7FFFu + ((u >> 16) & 1u)) >> 16);
}

// Async global->LDS staging (m97 lever). LDS dest is wave-uniform base + lane*16 in our
// staging pattern (consecutive tid -> consecutive 16B LDS chunks), which is the documented
// contract. Fallback: plain vector copy (same data, VGPR round-trip).
#if defined(__has_builtin) && __has_builtin(__builtin_amdgcn_global_load_lds)
#define GLOAD_LDS(gp, lp)                                            \
  __builtin_amdgcn_global_load_lds(                                  \
      (const __attribute__((address_space(1))) void*)(gp),           \
      (__attribute__((address_space(3))) void*)(lp), 16, 0, 0)
#else
#define GLOAD_LDS(gp, lp) do { *(uint4*)(lp) = *(const uint4*)(gp); } while (0)
#endif

// f32 -> bf16 RNE convert, two regions per launch (launch-count diet). Same f2bf as the
// validated inline path -> bit-identical GEMM inputs. src2 may be null.
__global__ void __launch_bounds__(256) conv_f2bf_kernel(
    const float* __restrict__ src1, unsigned short* __restrict__ dst1, int n1,
    const float* __restrict__ src2, unsigned short* __restrict__ dst2, int n2)
{
  int id = blockIdx.x * 256 + threadIdx.x;
  const float* src; unsigned short* dst; int i;
  if (id < n1) { src = src1; dst = dst1; i = id; }
  else { i = id - n1; if (i >= n2) return; src = src2; dst = dst2; }
  const float4* s = (const float4*)src + (size_t)i * 2;
  float4 a0 = s[0], a1 = s[1];
  uint4 u;
  u.x = (uint32_t)f2bf(a0.x) | ((uint32_t)f2bf(a0.y) << 16);
  u.y = (uint32_t)f2bf(a0.z) | ((uint32_t)f2bf(a0.w) << 16);
  u.z = (uint32_t)f2bf(a1.x) | ((uint32_t)f2bf(a1.y) << 16);
  u.w = (uint32_t)f2bf(a1.z) | ((uint32_t)f2bf(a1.w) << 16);
  ((uint4*)dst)[i] = u;
}

// Batched QKV projection: C_z = X_z @ W_z^T + b_z, z=0,1,2 (query/key/value).
// R9 theory: 3 separate GEMMs at grid 256 = 1 block/CU each (occupancy trap, same root
// cause as assign2's R8/R9 stalls). Batching via gridDim.z=3 -> 768 blocks = 3 blocks/CU,
// the regime where the m97 structure measured ~900 TF. A staged with INLINE f32->bf16
// convert (R0-R3-validated path, bit-identical f2bf) so no 24MB pre-converted X needed;
// B (bf16, pre-converted) via global_load_lds. MFMA frag/epilogue = validated structure.
__global__ void __launch_bounds__(256) gemm_qkv_mfma(
    const float* __restrict__ Aq, const float* __restrict__ Ak, const float* __restrict__ Av,
    const unsigned short* __restrict__ Wall,   // 3 x EMB*EMB bf16, z-contiguous
    const float* __restrict__ bq_, const float* __restrict__ bk_, const float* __restrict__ bv_,
    unsigned short* __restrict__ Qb, unsigned short* __restrict__ Kb, unsigned short* __restrict__ Vb)
{
  int z = blockIdx.z;
  const float* A = (z == 0) ? Aq : (z == 1) ? Ak : Av;
  const unsigned short* B = Wall + (size_t)z * EMB * EMB;
  const float* bias = (z == 0) ? bq_ : (z == 1) ? bk_ : bv_;
  unsigned short* outB = (z == 0) ? Qb : (z == 1) ? Kb : Vb;

  __shared__ __align__(16) unsigned short As[128][32];  // unpadded 64B rows (b128-aligned)
  __shared__ __align__(16) unsigned short Bs[128][32];
  const int K = EMB;
  int tid = threadIdx.x;
  int m0 = blockIdx.y * 128, n0 = blockIdx.x * 128;
  int wave = tid >> 6, lane = tid & 63;
  int wm = (wave >> 1) * 64, wn = (wave & 1) * 64;

  f32x4 zero = {0.f, 0.f, 0.f, 0.f};
  f32x4 acc[4][4];
#pragma unroll
  for (int mi = 0; mi < 4; mi++)
#pragma unroll
    for (int ni = 0; ni < 4; ni++) acc[mi][ni] = zero;

  int fr = lane & 15, fk = (lane >> 4) * 8;

  for (int k0 = 0; k0 < K; k0 += 32) {
    __syncthreads();
#pragma unroll
    for (int it = 0; it < 2; it++) {
      int ch = tid + it * 256;          // 512 chunks of 8 elems per tile
      int row = ch >> 2, kk = (ch & 3) * 8;
      {                                 // A: f32 global, inline RNE convert (R0-validated)
        const float* ap = A + (size_t)(m0 + row) * K + k0 + kk;
        float4 a0 = *(const float4*)ap, a1 = *(const float4*)(ap + 4);
        uint4 u;
        u.x = (uint32_t)f2bf(a0.x) | ((uint32_t)f2bf(a0.y) << 16);
        u.y = (uint32_t)f2bf(a0.z) | ((uint32_t)f2bf(a0.w) << 16);
        u.z = (uint32_t)f2bf(a1.x) | ((uint32_t)f2bf(a1.y) << 16);
        u.w = (uint32_t)f2bf(a1.z) | ((uint32_t)f2bf(a1.w) << 16);
        *(uint4*)(&As[row][kk]) = u;
      }
      GLOAD_LDS(B + (size_t)(n0 + row) * K + k0 + kk, &Bs[row][kk]);
    }
    __syncthreads();
    bf16x8 af[4], bfr[4];
#pragma unroll
    for (int i = 0; i < 4; i++) af[i] = *(const bf16x8*)(&As[wm + i * 16 + fr][fk]);
#pragma unroll
    for (int i = 0; i < 4; i++) bfr[i] = *(const bf16x8*)(&Bs[wn + i * 16 + fr][fk]);
#pragma unroll
    for (int mi = 0; mi < 4; mi++)
#pragma unroll
      for (int ni = 0; ni < 4; ni++)
        acc[mi][ni] = __builtin_amdgcn_mfma_f32_16x16x32_bf16(af[mi], bfr[ni], acc[mi][ni], 0, 0, 0);
  }

#pragma unroll
  for (int ni = 0; ni < 4; ni++) {
    int col = n0 + wn + ni * 16 + (lane & 15);
    float bv = bias[col];
#pragma unroll
    for (int mi = 0; mi < 4; mi++) {
#pragma unroll
      for (int r = 0; r < 4; r++) {
        int row = m0 + wm + mi * 16 + (lane >> 4) * 4 + r;
        outB[(size_t)row * EMB + col] = f2bf(acc[mi][ni][r] + bv);
      }
    }
  }
}

// C = A @ B^T + bias, A bf16 workspace, B bf16 pre-converted. (Wo projection only.)
// m93/m97-validated frag/epilogue structure; staging pure global_load_lds width-16.
__global__ void __launch_bounds__(256) gemm_bt_mfma(
    const unsigned short* __restrict__ A, const unsigned short* __restrict__ B,
    const float* __restrict__ bias,
    float* __restrict__ outF)
{
  __shared__ __align__(16) unsigned short As[128][32];
  __shared__ __align__(16) unsigned short Bs[128][32];
  const int K = EMB;
  int tid = threadIdx.x;
  int m0 = blockIdx.y * 128, n0 = blockIdx.x * 128;
  int wave = tid >> 6, lane = tid & 63;
  int wm = (wave >> 1) * 64, wn = (wave & 1) * 64;

  f32x4 zero = {0.f, 0.f, 0.f, 0.f};
  f32x4 acc[4][4];
#pragma unroll
  for (int mi = 0; mi < 4; mi++)
#pragma unroll
    for (int ni = 0; ni < 4; ni++) acc[mi][ni] = zero;

  int fr = lane & 15, fk = (lane >> 4) * 8;

  for (int k0 = 0; k0 < K; k0 += 32) {
    __syncthreads();
#pragma unroll
    for (int it = 0; it < 2; it++) {
      int ch = tid + it * 256;
      int row = ch >> 2, kk = (ch & 3) * 8;
      GLOAD_LDS(A + (size_t)(m0 + row) * K + k0 + kk, &As[row][kk]);
      GLOAD_LDS(B + (size_t)(n0 + row) * K + k0 + kk, &Bs[row][kk]);
    }
    __syncthreads();
    bf16x8 af[4], bfr[4];
#pragma unroll
    for (int i = 0; i < 4; i++) af[i] = *(const bf16x8*)(&As[wm + i * 16 + fr][fk]);
#pragma unroll
    for (int i = 0; i < 4; i++) bfr[i] = *(const bf16x8*)(&Bs[wn + i * 16 + fr][fk]);
#pragma unroll
    for (int mi = 0; mi < 4; mi++)
#pragma unroll
      for (int ni = 0; ni < 4; ni++)
        acc[mi][ni] = __builtin_amdgcn_mfma_f32_16x16x32_bf16(af[mi], bfr[ni], acc[mi][ni], 0, 0, 0);
  }

#pragma unroll
  for (int ni = 0; ni < 4; ni++) {
    int col = n0 + wn + ni * 16 + (lane & 15);
    float bv = bias[col];
#pragma unroll
    for (int mi = 0; mi < 4; mi++) {
#pragma unroll
      for (int r = 0; r < 4; r++) {
        int row = m0 + wm + mi * 16 + (lane >> 4) * 4 + r;
        outF[(size_t)row * EMB + col] = acc[mi][ni][r] + bv;
      }
    }
  }
}

// prep stage 1: partial[es][c][k] = sum_{e in es-chunk, ascending} W[e][k]*cent[c][e], f64.
// (R7-validated: prep family now ~7us.) W reads coalesced 256B row-runs; cent rows
// wave-uniform (readfirstlane -> s_load); 8 independent f64 FMA chains.
__global__ void __launch_bounds__(256) prep_partial_kernel(
    const float* __restrict__ Wq_, const float* __restrict__ cq_,
    const float* __restrict__ Wk_, const float* __restrict__ ck_,
    double* __restrict__ partQ, double* __restrict__ partK)
{
  const float* W; const float* cent; double* part;
  if (blockIdx.z == 0) { W = Wq_; cent = cq_; part = partQ; }
  else                 { W = Wk_; cent = ck_; part = partK; }
  int tid = threadIdx.x;
  int k = (blockIdx.y << 6) | (tid & 63);
  int cbase = __builtin_amdgcn_readfirstlane(tid >> 6) * 8;   // wave-uniform -> s_load path
  int e0 = blockIdx.x << 6;

  double acc[8];
#pragma unroll
  for (int j = 0; j < 8; j++) acc[j] = 0.0;

#pragma unroll 2
  for (int e = 0; e < 64; e++) {
    double w = (double)W[(size_t)(e0 + e) * EMB + k];
#pragma unroll
    for (int j = 0; j < 8; j++)
      acc[j] += w * (double)cent[(size_t)(cbase + j) * EMB + e0 + e];
  }
#pragma unroll
  for (int j = 0; j < 8; j++)
    part[((size_t)blockIdx.x * NC + cbase + j) * EMB + k] = acc[j];
}

// prep stage 2: WcT[k][c] = sum_{es ascending} partial[es][c][k]  (globally e-ascending
// f64 order, deterministic).
__global__ void __launch_bounds__(256) prep_reduce_kernel(
    const double* __restrict__ partQ, const double* __restrict__ partK,
    double* __restrict__ WcTq, double* __restrict__ WcTk)
{
  int id = blockIdx.x * 256 + threadIdx.x;        // 0 .. 2*NC*EMB-1
  const double* part; double* WcT; int local;
  if (id < NC * EMB) { part = partQ; WcT = WcTq; local = id; }
  else               { part = partK; WcT = WcTk; local = id - NC * EMB; }
  int c = local >> 10, k = local & 1023;
  double s = 0.0;
  for (int es = 0; es < 16; es++)
    s += part[((size_t)es * NC + c) * EMB + k];
  WcT[(size_t)k * NC + c] = s;
}

// bd[c] = sum_e bias[e]*cent[c][e] — bit-identical replica of the original bd path
// (8 g-groups of 128 consecutive e, then g-ordered sum). blockIdx.x: 0=q, 1=k.
__global__ void __launch_bounds__(256) prep_bd_kernel(
    const float* __restrict__ bq_, const float* __restrict__ cq_,
    const float* __restrict__ bk_, const float* __restrict__ ck_,
    double* __restrict__ bdq, double* __restrict__ bdk)
{
  const float* bias; const float* cent; double* bd;
  if (blockIdx.x == 0) { bias = bq_; cent = cq_; bd = bdq; }
  else                 { bias = bk_; cent = ck_; bd = bdk; }
  int tid = threadIdx.x;
  int c = tid & 31, g = tid >> 5;
  __shared__ double red[8][32];
  double s2 = 0.0;
  for (int e = g * 128; e < (g + 1) * 128; e++)
    s2 += (double)bias[e] * (double)cent[(size_t)c * EMB + e];
  red[g][c] = s2;
  __syncthreads();
  if (tid < 32) {
    double t = 0.0;
#pragma unroll
    for (int gg = 0; gg < 8; gg++) t += red[gg][tid];
    bd[tid] = t;
  }
}

// Assignment from RAW f32 input rows via WcT: f64 dots, first-max argmax.
// R8-MEASURED version (58.4us), reverted from R9's VMEM-broadcast variant (77us: at
// 1 block/CU the ~200cyc L1 latency is exposed; LDS's 12cyc issue cost was the cheaper
// trade). X staged f32 in LDS (one b128 = 4 k), 4 rows per c-group, Ws register-cached
// per 8-k step. blockIdx.y: 0=query, 1=key.
__global__ void __launch_bounds__(256) assign2_kernel(
    const float* __restrict__ Xq, const double* __restrict__ WcTq, const double* __restrict__ bdq,
    int* __restrict__ qcl, int* __restrict__ qcnt,
    const float* __restrict__ Xk, const double* __restrict__ WcTk, const double* __restrict__ bdk,
    int* __restrict__ kcl, int* __restrict__ kcnt)
{
  const float* X; const double* WcT; const double* bd; int* cluster; int* count;
  if (blockIdx.y == 0) { X = Xq; WcT = WcTq; bd = bdq; cluster = qcl; count = qcnt; }
  else                 { X = Xk; WcT = WcTk; bd = bdk; cluster = kcl; count = kcnt; }

  int r0 = blockIdx.x * 32;                       // 32 rows/block
  int tid = threadIdx.x;
  int c = tid & 31, g = tid >> 5;                 // 8 groups x 4 rows
  int g4 = g * 4;

  __shared__ __align__(16) double Ws[64][32];     // [kk][c] f64, 16 KB
  __shared__ __align__(16) float  Xs[32][64];     // [row][kk] f32, 8 KB

  double a[4][4];                                 // 4 rows x 4 k-phase chains
#pragma unroll
  for (int rr = 0; rr < 4; rr++)
#pragma unroll
    for (int j = 0; j < 4; j++) a[rr][j] = 0.0;

  for (int k0 = 0; k0 < EMB; k0 += 64) {
    __syncthreads();                              // prev chunk compute done
    // stage WcT chunk: 2048 doubles, 8/thread, coalesced
#pragma unroll
    for (int it = 0; it < 8; it++) {
      int idx = it * 256 + tid;
      ((double*)Ws)[idx] = WcT[(size_t)k0 * NC + idx];
    }
    // stage X chunk f32: 512 float4 pieces, 2/thread, coalesced
#pragma unroll
    for (int it = 0; it < 2; it++) {
      int idx = it * 256 + tid;
      int r = idx >> 4, kp = (idx & 15) * 4;
      *(float4*)(&Xs[r][kp]) = *(const float4*)(X + (size_t)(r0 + r) * EMB + k0 + kp);
    }
    __syncthreads();                              // tiles ready
#pragma unroll
    for (int ks = 0; ks < 64; ks += 8) {
      double w0 = Ws[ks + 0][c], w1 = Ws[ks + 1][c];
      double w2 = Ws[ks + 2][c], w3 = Ws[ks + 3][c];
      double w4 = Ws[ks + 4][c], w5 = Ws[ks + 5][c];
      double w6 = Ws[ks + 6][c], w7 = Ws[ks + 7][c];
#pragma unroll
      for (int rr = 0; rr < 4; rr++) {
        float4 xa = *(const float4*)(&Xs[g4 + rr][ks]);
        float4 xb = *(const float4*)(&Xs[g4 + rr][ks + 4]);
        a[rr][0] += (double)xa.x * w0; a[rr][1] += (double)xa.y * w1;
        a[rr][2] += (double)xa.z * w2; a[rr][3] += (double)xa.w * w3;
        a[rr][0] += (double)xb.x * w4; a[rr][1] += (double)xb.y * w5;
        a[rr][2] += (double)xb.z * w6; a[rr][3] += (double)xb.w * w7;
      }
    }
  }

  double bdc = bd[c];
#pragma unroll
  for (int rr = 0; rr < 4; rr++) {
    double dot = ((a[rr][0] + a[rr][1]) + (a[rr][2] + a[rr][3])) + bdc;
    // argmax over c within each 32-lane half (first-max: lowest index wins ties)
    double bv = dot; int bi = c;
#pragma unroll
    for (int off = 1; off < 32; off <<= 1) {
      double ov = __shfl_xor(bv, off, 64);
      int oi = __shfl_xor(bi, off, 64);
      if (ov > bv || (ov == bv && oi < bi)) { bv = ov; bi = oi; }
    }
    if (c == 0) {
      int row = r0 + g4 + rr;
      cluster[row] = bi;
      atomicAdd(&count[(row & 1) * NC + bi], 1);
    }
  }
}

__global__ void scan_kernel(const int* __restrict__ qcount, const int* __restrict__ kcount,
                            int* __restrict__ qoff, int* __restrict__ koff)
{
  int tid = threadIdx.x;
  if (tid < 2) {
    int run = 0;
    for (int c = 0; c < NC; c++) { qoff[tid * NC + c] = run; run += qcount[tid * NC + c]; }
  } else if (tid < 4) {
    int n = tid - 2, run = 0;
    for (int c = 0; c < NC; c++) { koff[n * NC + c] = run; run += kcount[n * NC + c]; }
  }
}

__global__ void __launch_bounds__(256) scatter_kernel(
    const int* __restrict__ q_cluster, const int* __restrict__ k_cluster,
    const int* __restrict__ qoff, const int* __restrict__ koff,
    int* __restrict__ qfill, int* __restrict__ kfill,
    int* __restrict__ qlist, int* __restrict__ klist)
{
  int id = blockIdx.x * 256 + threadIdx.x;
  if (id < MROWS) {
    int row = id, n = row & 1, l = row >> 1, c = q_cluster[row];
    int pos = atomicAdd(&qfill[n * NC + c], 1);
    qlist[n * L_SEQ + qoff[n * NC + c] + pos] = l;
  } else {
    int row = id - MROWS, n = row & 1, s = row >> 1, c = k_cluster[row];
    int pos = atomicAdd(&kfill[n * NC + c], 1);
    klist[n * S_SEQ + koff[n * NC + c] + pos] = s;
  }
}

// Bucketed attention, MFMA flash-style. Block=(cluster,head,batch), 4 waves, 16 queries/wave,
// 64-key chunks with online softmax. Swapped operands keep softmax per-lane-uniform:
//   S^T = mfma(A=K, B=Q)    -> D[row=key=4g+r][col=q=lane&15]
//   O^T = mfma(A=V^T, B=P^T)-> D[row=d  =4g+r][col=q=lane&15]
// so running max / lsum / rescale are one scalar per lane (reduce = shfl_xor 16,32).
// P^T relayout through wave-private LDS; all LDS tiles row-XOR-swizzled. (R1-validated.)
__global__ void __launch_bounds__(256) attn_bucket(
    const unsigned short* __restrict__ Qb, const unsigned short* __restrict__ Kb,
    const unsigned short* __restrict__ Vb,
    const int* __restrict__ qcount, const int* __restrict__ qoff, const int* __restrict__ qlist,
    const int* __restrict__ kcount, const int* __restrict__ koff, const int* __restrict__ klist,
    unsigned short* __restrict__ ctx)
{
  int c = blockIdx.x, h = blockIdx.y, n = blockIdx.z;
  int Sc = kcount[n * NC + c], k0base = koff[n * NC + c];
  int Lc = qcount[n * NC + c], q0 = qoff[n * NC + c];
  int tid = threadIdx.x, wave = tid >> 6, lane = tid & 63;
  int lg = lane >> 4, lq = lane & 15;

  __shared__ __align__(16) unsigned short Ks[64][64];    // [key][d], row-swizzled
  __shared__ __align__(16) unsigned short Vts[64][64];   // [d][key], row-swizzled
  __shared__ __align__(16) unsigned short Pts[4][16][64]; // per-wave [q][key], row-swizzled
  __shared__ int rb[64];                                  // gathered K/V row base offsets

  if (Sc == 0) {   // no keys: ref softmax would be NaN; R9 proved this never occurs. Write 0.
    for (int qi = wave; qi < Lc; qi += 4) {
      int l = qlist[n * L_SEQ + q0 + qi];
      ctx[((size_t)(n * L_SEQ + l)) * EMB + h * DH + lane] = 0;
    }
    return;
  }

  const int* kl = klist + n * S_SEQ + k0base;
  const int* ql = qlist + n * L_SEQ + q0;
  f32x4 zero = {0.f, 0.f, 0.f, 0.f};

  for (int qb = 0; qb < Lc; qb += 64) {           // uniform trip count across waves
    int qq = qb + wave * 16 + lq;
    int qqc = qq < Lc ? qq : Lc - 1;              // clamp: padded lanes duplicate last query
    int lrow = ql[qqc];
    const unsigned short* qp = Qb + ((size_t)(lrow * NB + n)) * EMB + h * DH;
    bf16x8 qf0 = *(const bf16x8*)(qp + lg * 8);          // B=Q frag: col=q, k=d 0..31
    bf16x8 qf1 = *(const bf16x8*)(qp + 32 + lg * 8);     //                  d 32..63

    f32x4 acc[4];                                  // O^T: 4 d-tiles, col=q per lane
#pragma unroll
    for (int di = 0; di < 4; di++) acc[di] = zero;
    float m = -3.0e38f, lsum = 0.f;

    for (int kc = 0; kc < Sc; kc += 64) {
      __syncthreads();                             // prev chunk compute done
      if (tid < 64) {
        int jj = kc + tid; if (jj >= Sc) jj = Sc - 1;   // clamp-pad: valid finite rows
        rb[tid] = (kl[jj] * NB + n) * EMB + h * DH;
      }
      __syncthreads();                             // rb ready
#pragma unroll
      for (int it = 0; it < 2; it++) {
        int p = it * 256 + tid;                    // 512 pieces
        {                                          // K: [key][d] 16B pieces
          int row = p >> 3, seg = p & 7;
          uint4 u = *(const uint4*)(Kb + rb[row] + seg * 8);
          *(uint4*)(&Ks[row][(seg * 8) ^ ((row & 7) << 3)]) = u;
        }
        {                                          // V^T: gather column d, 8 keys
          int d = p & 63, kg = p >> 6;
          unsigned short v0 = Vb[rb[kg * 8 + 0] + d], v1 = Vb[rb[kg * 8 + 1] + d];
          unsigned short v2 = Vb[rb[kg * 8 + 2] + d], v3 = Vb[rb[kg * 8 + 3] + d];
          unsigned short v4 = Vb[rb[kg * 8 + 4] + d], v5 = Vb[rb[kg * 8 + 5] + d];
          unsigned short v6 = Vb[rb[kg * 8 + 6] + d], v7 = Vb[rb[kg * 8 + 7] + d];
          uint4 u;
          u.x = (uint32_t)v0 | ((uint32_t)v1 << 16);
          u.y = (uint32_t)v2 | ((uint32_t)v3 << 16);
          u.z = (uint32_t)v4 | ((uint32_t)v5 << 16);
          u.w = (uint32_t)v6 | ((uint32_t)v7 << 16);
          *(uint4*)(&Vts[d][(kg * 8) ^ ((d & 7) << 3)]) = u;
        }
      }
      __syncthreads();                             // K/V^T staged

      // S^T = K @ Q^T : 4 key-tiles x 2 d-steps
      f32x4 st[4];
#pragma unroll
      for (int ni = 0; ni < 4; ni++) st[ni] = zero;
#pragma unroll
      for (int ni = 0; ni < 4; ni++) {
        int row = ni * 16 + lq;
        bf16x8 kf0 = *(const bf16x8*)(&Ks[row][(lg * 8) ^ ((row & 7) << 3)]);
        bf16x8 kf1 = *(const bf16x8*)(&Ks[row][(32 + lg * 8) ^ ((row & 7) << 3)]);
        st[ni] = __builtin_amdgcn_mfma_f32_16x16x32_bf16(kf0, qf0, st[ni], 0, 0, 0);
        st[ni] = __builtin_amdgcn_mfma_f32_16x16x32_bf16(kf1, qf1, st[ni], 0, 0, 0);
      }

      // online softmax (per-lane scalar state; clamp-padded keys duplicate valid
      // scores so they cannot change the max; they are zeroed in p below)
      int lim = Sc - kc;
      float cm = -3.0e38f;
#pragma unroll
      for (int ni = 0; ni < 4; ni++) {
        st[ni] = st[ni] * 0.125f;                  // 1/sqrt(64)
#pragma unroll
        for (int r = 0; r < 4; r++) cm = fmaxf(cm, st[ni][r]);
      }
      cm = fmaxf(cm, __shfl_xor(cm, 16, 64));
      cm = fmaxf(cm, __shfl_xor(cm, 32, 64));
      float mn = fmaxf(m, cm);
      float fac = __expf(m - mn);
      m = mn;
      lsum *= fac;
#pragma unroll
      for (int di = 0; di < 4; di++) acc[di] = acc[di] * fac;

      // P^T -> LDS (bf16); lsum over ROUNDED p so O stays a true weighted average
#pragma unroll
      for (int ni = 0; ni < 4; ni++) {
        int kloc = ni * 16 + lg * 4;
        float p0 = (kloc + 0 < lim) ? __expf(st[ni][0] - mn) : 0.f;
        float p1 = (kloc + 1 < lim) ? __expf(st[ni][1] - mn) : 0.f;
        float p2 = (kloc + 2 < lim) ? __expf(st[ni][2] - mn) : 0.f;
        float p3 = (kloc + 3 < lim) ? __expf(st[ni][3] - mn) : 0.f;
        unsigned short b0 = f2bf(p0), b1 = f2bf(p1), b2 = f2bf(p2), b3 = f2bf(p3);
        lsum += bf2f(b0) + bf2f(b1) + bf2f(b2) + bf2f(b3);
        ushort4 u4; u4.x = b0; u4.y = b1; u4.z = b2; u4.w = b3;
        *(ushort4*)(&Pts[wave][lq][kloc ^ ((lq & 7) << 3)]) = u4;
      }

      // O^T += V^T @ P^T : 4 d-tiles x 2 key-steps
#pragma unroll
      for (int ks = 0; ks < 2; ks++) {
        bf16x8 pf = *(const bf16x8*)(&Pts[wave][lq][(ks * 32 + lg * 8) ^ ((lq & 7) << 3)]);
#pragma unroll
        for (int di = 0; di < 4; di++) {
          int row = di * 16 + lq;
          bf16x8 vf = *(const bf16x8*)(&Vts[row][(ks * 32 + lg * 8) ^ ((row & 7) << 3)]);
          acc[di] = __builtin_amdgcn_mfma_f32_16x16x32_bf16(vf, pf, acc[di], 0, 0, 0);
        }
      }
    }

    lsum += __shfl_xor(lsum, 16, 64);
    lsum += __shfl_xor(lsum, 32, 64);
    float rinv = 1.f / lsum;
    if (qq < Lc) {                                 // padded duplicates skip the store
      unsigned short* op = ctx + ((size_t)(n * L_SEQ + lrow)) * EMB + h * DH;
#pragma unroll
      for (int di = 0; di < 4; di++) {
        ushort4 o;
        o.x = f2bf(acc[di][0] * rinv);
        o.y = f2bf(acc[di][1] * rinv);
        o.z = f2bf(acc[di][2] * rinv);
        o.w = f2bf(acc[di][3] * rinv);
        *(ushort4*)(op + di * 16 + lg * 4) = o;    // d = di*16 + 4g + r, contiguous r
      }
    }
  }
}

// Residual + LayerNorm, f32 output. out row r = l*NB+n; proj row = n*L+l. (R9-validated.)
__global__ void __launch_bounds__(256) ln_kernel(
    const float* __restrict__ proj, const float* __restrict__ query,
    const float* __restrict__ gamma, const float* __restrict__ beta,
    float* __restrict__ out)
{
  int r = blockIdx.x;
  int l = r >> 1, n = r & 1;
  int tid = threadIdx.x, wave = tid >> 6, lane = tid & 63;
  float4 p = *(const float4*)(proj + ((size_t)(n * L_SEQ + l)) * EMB + tid * 4);
  float4 qu = *(const float4*)(query + (size_t)r * EMB + tid * 4);
  float res[4] = { p.x + qu.x, p.y + qu.y, p.z + qu.z, p.w + qu.w };
  float s1 = res[0] + res[1] + res[2] + res[3];
  float s2 = res[0] * res[0] + res[1] * res[1] + res[2] * res[2] + res[3] * res[3];
#pragma unroll
  for (int off = 32; off; off >>= 1) {
    s1 += __shfl_xor(s1, off, 64);
    s2 += __shfl_xor(s2, off, 64);
  }
  __shared__ float a1[4], a2[4];
  if (lane == 0) { a1[wave] = s1; a2[wave] = s2; }
  __syncthreads();
  float t1 = a1[0] + a1[1] + a1[2] + a1[3];
  float t2 = a2[0] + a2[1] + a2[2] + a2[3];
  float mu = t1 * (1.f / EMB);
  float var = fmaxf(t2 * (1.f / EMB) - mu * mu, 0.f);
  float rstd = 1.f / sqrtf(var + 1e-5f);
  float4 gu = *(const float4*)(gamma + tid * 4);
  float4 bu = *(const float4*)(beta + tid * 4);
  float4 o;
  o.x = (res[0] - mu) * rstd * gu.x + bu.x;
  o.y = (res[1] - mu) * rstd * gu.y + bu.y;
  o.z = (res[2] - mu) * rstd * gu.z + bu.z;
  o.w = (res[3] - mu) * rstd * gu.w + bu.w;
  *(float4*)(out + (size_t)r * EMB + tid * 4) = o;
}

extern "C" void kernel_launch(void* const* d_in, const int* in_sizes, int n_in,
                              void* d_out, int out_size, void* d_ws, size_t ws_size,
                              hipStream_t stream) {
  const float* query = (const float*)d_in[0];
  const float* key   = (const float*)d_in[1];
  const float* value = (const float*)d_in[2];
  const float* Wq = (const float*)d_in[3];
  const float* bq = (const float*)d_in[4];
  const float* Wk = (const float*)d_in[5];
  const float* bk = (const float*)d_in[6];
  const float* Wv = (const float*)d_in[7];
  const float* bv = (const float*)d_in[8];
  const float* Wo = (const float*)d_in[9];
  const float* bo = (const float*)d_in[10];
  const float* cq = (const float*)d_in[11];
  const float* ck = (const float*)d_in[12];
  const float* gamma = (const float*)d_in[13];
  const float* beta  = (const float*)d_in[14];
  float* out = (float*)d_out;   // f32 output (reference dtype)

  const size_t MB_EL = (size_t)MROWS * EMB;   // 4M elements

  // workspace (~35 MB): control block first, then bf16 tensors; proj aliases Qb+Kb;
  // wqkv (6 MB bf16 QKV weights) aliases ctx (dead until attention overwrites);
  // wbf (2 MB, Wo weights) appended; prep partials (8 MB) alias Qb (consumed pre-GEMM).
  int* q_cluster = (int*)d_ws;               // 16 KB
  int* k_cluster = q_cluster + MROWS;        // 16 KB
  int* qcount = k_cluster + MROWS;           // 6 x 64 ints contiguous (one memset)
  int* kcount = qcount + 64;
  int* qoff   = kcount + 64;
  int* koff   = qoff + 64;
  int* qfill  = koff + 64;
  int* kfill  = qfill + 64;
  int* qlist  = kfill + 64;                  // [2][2048]
  int* klist  = qlist + MROWS;               // [2][2048]
  double* Wcq = (double*)(klist + MROWS);    // 256 KB (offset 67072, 16B-aligned) [k][c] layout
  double* Wck = Wcq + (size_t)NC * EMB;      // 256 KB [k][c] layout
  double* bdq = Wck + (size_t)NC * EMB;
  double* bdk = bdq + NC;
  unsigned short* Qb  = (unsigned short*)(bdk + NC);  // 8 MB bf16, row = seq*2+n
  unsigned short* Kb  = Qb + MB_EL;                   // 8 MB
  unsigned short* Vb  = Kb + MB_EL;                   // 8 MB
  unsigned short* ctx = Vb + MB_EL;                   // 8 MB, row = n*L+l
  unsigned short* wbf = ctx + MB_EL;                  // 2 MB bf16 Wo scratch
  unsigned short* wqkv = ctx;  // 6 MB bf16 Wq|Wk|Wv overlay ctx (dead until attn writes)
  float* proj = (float*)Qb;    // 16 MB f32 overlays Qb+Kb (dead after attention)
  double* partQ = (double*)Qb; // 4 MB prep partials overlay Qb (consumed before GEMM)
  double* partK = partQ + (size_t)16 * NC * EMB;      // 4 MB

  const int W8 = (EMB * EMB) / 8;     // 131072 chunks per weight matrix

  hipMemsetAsync(qcount, 0, 6 * 64 * sizeof(int), stream);

  prep_partial_kernel<<<dim3(16, 16, 2), 256, 0, stream>>>(Wq, cq, Wk, ck, partQ, partK);
  prep_reduce_kernel<<<(2 * NC * EMB) / 256, 256, 0, stream>>>(partQ, partK, Wcq, Wck);
  prep_bd_kernel<<<2, 256, 0, stream>>>(bq, cq, bk, ck, bdq, bdk);

  // weight converts: Wq|Wk into wqkv[0..2), Wv into wqkv[2), Wo into wbf (2 launches)
  conv_f2bf_kernel<<<(2 * W8 + 255) / 256, 256, 0, stream>>>(
      Wq, wqkv, W8, Wk, wqkv + (size_t)EMB * EMB, W8);
  conv_f2bf_kernel<<<(2 * W8 + 255) / 256, 256, 0, stream>>>(
      Wv, wqkv + (size_t)2 * EMB * EMB, W8, Wo, wbf, W8);

  // batched QKV projections: grid.z = 3 -> 768 blocks = 3 blocks/CU
  dim3 gq(EMB / 128, MROWS / 128, 3);
  gemm_qkv_mfma<<<gq, 256, 0, stream>>>(query, key, value, wqkv, bq, bk, bv, Qb, Kb, Vb);

  assign2_kernel<<<dim3(MROWS / 32, 2), 256, 0, stream>>>(
      query, Wcq, bdq, q_cluster, qcount,
      key,   Wck, bdk, k_cluster, kcount);

  scan_kernel<<<1, 64, 0, stream>>>(qcount, kcount, qoff, koff);
  scatter_kernel<<<(2 * MROWS) / 256, 256, 0, stream>>>(q_cluster, k_cluster, qoff, koff,
                                                        qfill, kfill, qlist, klist);
  attn_bucket<<<dim3(NC, NH, NB), 256, 0, stream>>>(Qb, Kb, Vb, qcount, qoff, qlist,
                                                    kcount, koff, klist, ctx);

  dim3 gg(EMB / 128, MROWS / 128);
  gemm_bt_mfma<<<gg, 256, 0, stream>>>(ctx, wbf, bo, proj);
  ln_kernel<<<MROWS, 256, 0, stream>>>(proj, query, gamma, beta, out);
}